// Round 17
// baseline (486.598 us; speedup 1.0000x reference)
//
#include <hip/hip_runtime.h>
#include <cstdint>
#include <cstddef>

#define KNN 16
#define NPTS 256
#define NBATCH 128

static constexpr float BN_SCALE_F = 0.9999950000374997f; // 1/sqrt(1+1e-5)

__device__ inline unsigned int f32_ord(float f) {
    unsigned int u = __float_as_uint(f);
    return (u & 0x80000000u) ? ~u : (u | 0x80000000u);
}

// Ws column gap map: 16-blocks shifted by 4 banks.
__device__ __forceinline__ int wmap(int n) { return n + 4 * (n >> 4); }

// ---------------------------------------------------------------------------
// FUSED kNN v11 = v9s with 1024 threads (16 waves = 4 waves/SIMD — doubling
// the intra-block TLP that was the session's one effective lever; r12 win).
// Same block tile (128 i x 256 j, grid 256); per thread: acc[4][8]
// (ty = t>>5 owns rows ty*4..+3), 8 selection channels/row (sch = t&7,
// cands j = ph*128 + sch + 8i, ascending per channel), 8-way
// (value,index)-lex merge. Mi widened to [128][132]. sq in-kernel as v9s.
// launch_bounds(1024) forces VGPR<=128; acc halved 64->32 regs makes this
// fit (~100 expected). SPILL TRIPWIRE: WRITE_SIZE >> 8 MB => revert.
// Same k-ascending fmaf chain + epilogue expr + strict-< ladder -> bit-identical.
// ---------------------------------------------------------------------------
template<int D>
__global__ __launch_bounds__(1024) void knn_fused_kernel(
        const float* __restrict__ x, int* __restrict__ idx) {
    constexpr int KS = (D >= 16) ? 16 : D;
    constexpr int NSTEP = D / KS;                     // 8 / 4 / 1
    constexpr int NLA = (128 * KS + 1023) / 1024;     // generic A loads
    constexpr int NLB = (256 * KS + 1023) / 1024;     // generic B loads
    const int t  = threadIdx.x;
    const int tx = t & 31, ty = t >> 5;               // ty 0..31
    const int sr = t >> 3, sch = t & 7;               // 128 rows x 8 channels
    const int b  = blockIdx.x >> 1;
    const int i0 = (blockIdx.x & 1) * 128;
    const int base = b * NPTS;

    __shared__ float As[2][KS][132];         // 128-row A k-slab, dbuf
    __shared__ float Bs[2][KS][260];         // 256-row B k-slab, dbuf
    __shared__ float d2L[128][132];          // per-phase d2 + merge values
    __shared__ unsigned char Mi[128][132];   // merge indices (8 ch x 16)
    __shared__ float sqS[256];               // in-kernel sq

    // ---- prefetch registers; issue loads for slab s=0 ----
    float4 pa, pb;
    float  pas[NLA], pbs[NLB];
    if constexpr (D % 16 == 0) {
        if (t < 512) {                        // A: 512 quads
            const int r = t >> 2, cq = (t & 3) * 4;
            pa = *(const float4*)(x + (size_t)(base + i0 + r) * D + cq);
        }
        {                                     // B: 1024 quads, one each
            const int r = t >> 2, cq = (t & 3) * 4;
            pb = *(const float4*)(x + (size_t)(base + r) * D + cq);
        }
    } else {
        #pragma unroll
        for (int u = 0; u < NLA; ++u) {
            const int e = t + u * 1024;
            if (e < 128 * KS) {
                const int r = e / KS, c = e % KS;
                pas[u] = x[(size_t)(base + i0 + r) * D + c];
            }
        }
        #pragma unroll
        for (int u = 0; u < NLB; ++u) {
            const int e = t + u * 1024;
            if (e < 256 * KS) {
                const int r = e / KS, c = e % KS;
                pbs[u] = x[(size_t)(base + r) * D + c];
            }
        }
    }

    // ---- compute sq for all 256 batch points (same fmaf chain as before) ----
    if (t < 256) {
        const float* r = x + (size_t)(base + t) * D;
        float ssum = 0.f;
        #pragma unroll
        for (int d = 0; d < D; ++d) ssum = fmaf(r[d], r[d], ssum);
        sqS[t] = ssum;
    }
    __syncthreads();

    // ---- hoist sqi (phase-invariant) ----
    float sqi[4];
    #pragma unroll
    for (int m = 0; m < 4; ++m) sqi[m] = sqS[i0 + ty * 4 + m];

    float acc[4][8] = {};

    for (int s = 0; s < NSTEP; ++s) {
        const int buf = s & 1;
        // ---- write prefetched A/B slabs into buf ----
        if constexpr (D % 16 == 0) {
            if (t < 512) {
                const int r = t >> 2, cq = (t & 3) * 4;
                As[buf][cq + 0][r] = pa.x; As[buf][cq + 1][r] = pa.y;
                As[buf][cq + 2][r] = pa.z; As[buf][cq + 3][r] = pa.w;
            }
            {
                const int r = t >> 2, cq = (t & 3) * 4;
                Bs[buf][cq + 0][r] = pb.x; Bs[buf][cq + 1][r] = pb.y;
                Bs[buf][cq + 2][r] = pb.z; Bs[buf][cq + 3][r] = pb.w;
            }
        } else {
            #pragma unroll
            for (int u = 0; u < NLA; ++u) {
                const int e = t + u * 1024;
                if (e < 128 * KS) {
                    const int r = e / KS, c = e % KS;
                    As[buf][c][r] = pas[u];
                }
            }
            #pragma unroll
            for (int u = 0; u < NLB; ++u) {
                const int e = t + u * 1024;
                if (e < 256 * KS) {
                    const int r = e / KS, c = e % KS;
                    Bs[buf][c][r] = pbs[u];
                }
            }
        }

        // ---- issue next slab's loads (hide under FMA block below) ----
        if (s + 1 < NSTEP) {
            const int k0n = (s + 1) * KS;
            if constexpr (D % 16 == 0) {
                if (t < 512) {
                    const int r = t >> 2, cq = (t & 3) * 4;
                    pa = *(const float4*)(x + (size_t)(base + i0 + r) * D + k0n + cq);
                }
                {
                    const int r = t >> 2, cq = (t & 3) * 4;
                    pb = *(const float4*)(x + (size_t)(base + r) * D + k0n + cq);
                }
            } else {
                #pragma unroll
                for (int u = 0; u < NLA; ++u) {
                    const int e = t + u * 1024;
                    if (e < 128 * KS) {
                        const int r = e / KS, c = e % KS;
                        pas[u] = x[(size_t)(base + i0 + r) * D + k0n + c];
                    }
                }
                #pragma unroll
                for (int u = 0; u < NLB; ++u) {
                    const int e = t + u * 1024;
                    if (e < 256 * KS) {
                        const int r = e / KS, c = e % KS;
                        pbs[u] = x[(size_t)(base + r) * D + k0n + c];
                    }
                }
            }
        }

        __syncthreads();   // the ONLY barrier in the slab step

        // ---- gram FMAs (k ascending); B-frag scalar lane==bank reads ----
        #pragma unroll
        for (int kk = 0; kk < KS; ++kk) {
            float am[4], bm[8];
            *(float4*)&am[0] = *(const float4*)&As[buf][kk][ty * 4];  // bcast
            #pragma unroll
            for (int n = 0; n < 8; ++n)
                bm[n] = Bs[buf][kk][n * 32 + tx];  // bank = tx: conflict-free
            #pragma unroll
            for (int m = 0; m < 4; ++m)
                #pragma unroll
                for (int n = 0; n < 8; ++n)
                    acc[m][n] = fmaf(am[m], bm[n], acc[m][n]);
        }
        // no trailing barrier: next slab writes the OTHER buffer.
    }

    unsigned int Lv[16], Li[16];
    #pragma unroll
    for (int q = 0; q < 16; ++q) { Lv[q] = 0xFFFFFFFFu; Li[q] = 0u; }

    // ==== two 128-col phases: epilogue write + insertion scan ====
    #pragma unroll
    for (int ph = 0; ph < 2; ++ph) {
        float sqj[4];
        #pragma unroll
        for (int n2 = 0; n2 < 4; ++n2)
            sqj[n2] = sqS[ph * 128 + n2 * 32 + tx];
        #pragma unroll
        for (int m = 0; m < 4; ++m) {
            const int gi = i0 + ty * 4 + m;
            #pragma unroll
            for (int n2 = 0; n2 < 4; ++n2) {
                float v = (sqi[m] + sqj[n2]) - 2.f * acc[m][ph * 4 + n2];
                if (gi == ph * 128 + n2 * 32 + tx) v = INFINITY;
                d2L[ty * 4 + m][n2 * 32 + tx] = v;
            }
        }
        __syncthreads();

        // ---- insertion: thread (sr, sch) scans j = ph*128 + sch + 8i ----
        #pragma unroll 4
        for (int i = 0; i < 16; ++i) {
            const unsigned int v = f32_ord(d2L[sr][sch + 8 * i]);
            const unsigned int j = (unsigned int)(ph * 128 + sch + 8 * i);
            #pragma unroll
            for (int q = 15; q >= 1; --q) {
                const bool a = v < Lv[q];
                const bool c = v < Lv[q - 1];
                Lv[q] = a ? (c ? Lv[q - 1] : v) : Lv[q];
                Li[q] = a ? (c ? Li[q - 1] : j) : Li[q];
            }
            const bool a0 = v < Lv[0];
            Lv[0] = a0 ? v : Lv[0];
            Li[0] = a0 ? j : Li[0];
        }
        __syncthreads();   // insertion done before d2L is overwritten
    }

    // ---- merge staging: 8 channel lists (16 each) into d2L/Mi ----
    #pragma unroll
    for (int q = 0; q < 16; ++q) {
        d2L[sr][sch * 16 + q] = __uint_as_float(Lv[q]);
        Mi[sr][sch * 16 + q]  = (unsigned char)Li[q];
    }
    __syncthreads();

    if (t < 128) {
        const int row = t;
        int h[8];
        unsigned int cv[8], ci[8];
        #pragma unroll
        for (int c = 0; c < 8; ++c) {
            h[c]  = 0;
            cv[c] = __float_as_uint(d2L[row][c * 16]);
            ci[c] = Mi[row][c * 16];
        }
        int outj[16];
        #pragma unroll
        for (int rd = 0; rd < 16; ++rd) {
            unsigned int bv = cv[0], bi = ci[0];
            int bc = 0;
            #pragma unroll
            for (int c = 1; c < 8; ++c) {
                const bool tk = (cv[c] < bv) | ((cv[c] == bv) & (ci[c] < bi));
                bv = tk ? cv[c] : bv;
                bi = tk ? ci[c] : bi;
                bc = tk ? c     : bc;
            }
            outj[rd] = (int)bi;
            #pragma unroll
            for (int c = 0; c < 8; ++c) {
                if (c == bc) {
                    const int hn = h[c] + 1;
                    h[c] = hn;
                    if (hn < 16) {
                        cv[c] = __float_as_uint(d2L[row][c * 16 + hn]);
                        ci[c] = Mi[row][c * 16 + hn];
                    } else {
                        cv[c] = 0xFFFFFFFFu;
                    }
                }
            }
        }
        int4* op = (int4*)(idx + (size_t)(base + i0 + row) * KNN);
        op[0] = make_int4(outj[0],  outj[1],  outj[2],  outj[3]);
        op[1] = make_int4(outj[4],  outj[5],  outj[6],  outj[7]);
        op[2] = make_int4(outj[8],  outj[9],  outj[10], outj[11]);
        op[3] = make_int4(outj[12], outj[13], outj[14], outj[15]);
    }
}

// ---------------------------------------------------------------------------
// Factorized edge-MLP GEMM v2c (round-14/15/16 version — best measured mlp):
// 256 thr, BM=128, double-buffered, barrier BEFORE the load issue.
// Bit-identical output.
// ---------------------------------------------------------------------------
template<int D, int C>
__global__ __launch_bounds__(256) void mlp_gemm_kernel(
        const float* __restrict__ x, const float* __restrict__ W,
        const float* __restrict__ bias, const float* __restrict__ g,
        const float* __restrict__ be,
        float* __restrict__ A, float* __restrict__ Bv) {
    constexpr int BM = 128;
    constexpr int KT = (D >= 16) ? 16 : D;
    constexpr int NSTEP = D / KT;                    // 8 / 4 / 1
    constexpr int NXG = (BM * KT + 255) / 256;       // generic X loads
    constexpr int NWG = (KT * 128 + 255) / 256;      // generic W loads
    const int t  = threadIdx.x;
    const int tx = t & 15;   // col group (8 cols)
    const int ty = t >> 4;   // row group (8 rows)
    const int m0 = blockIdx.x * BM;
    const int n0 = blockIdx.y * 128;

    __shared__ float Xs[2][KT][132];
    __shared__ float Ws[2][KT][164];   // stride 164 == 4 mod 32

    float acc[8][8] = {};

    // staging roles (fast path)
    const int xr = t >> 1, xc = (t & 1) * 8;   // X: row 0..127, col 0 or 8
    const int wk = t >> 4, nq = (t & 15) * 8;  // W: k-row 0..15, col-8-block
    const int gn = n0 + nq;
    const bool isTop = (gn < C);
    const int wcol = isTop ? gn : (gn - C);
    const int mb = wmap(nq);

    // prefetch registers
    float4 px0, px1;             // X slab: 8 floats
    float4 wt0, wt1, wb0, wb1;   // W slab: top + bottom, raw
    float  pxg[NXG], pwg[NWG];   // generic path

    // ---- issue loads for step s=0 ----
    if constexpr (D % 16 == 0) {
        const float* xp = x + (size_t)(m0 + xr) * D + xc;
        px0 = *(const float4*)(xp);
        px1 = *(const float4*)(xp + 4);
        const float* pT = W + (size_t)wk * C + wcol;        // top rows (unused if !isTop)
        const float* pB = W + (size_t)(D + wk) * C + wcol;  // bottom rows
        wt0 = *(const float4*)(pT); wt1 = *(const float4*)(pT + 4);
        wb0 = *(const float4*)(pB); wb1 = *(const float4*)(pB + 4);
    } else {
        #pragma unroll
        for (int u = 0; u < NXG; ++u) {
            const int e = t + u * 256;
            if (e < BM * KT) {
                const int r = e / KT, c = e % KT;
                pxg[u] = x[(size_t)(m0 + r) * D + c];
            }
        }
        #pragma unroll
        for (int u = 0; u < NWG; ++u) {
            const int e = t + u * 256;
            if (e < KT * 128) {
                const int k = e >> 7, n = e & 127;
                const int g2 = n0 + n;
                pwg[u] = (g2 < C)
                    ? W[(size_t)k * C + g2] - W[(size_t)(D + k) * C + g2]
                    : W[(size_t)(D + k) * C + (g2 - C)];
            }
        }
    }

    for (int s = 0; s < NSTEP; ++s) {
        const int buf = s & 1;
        // ---- write staged slabs (loaded last step) into buf ----
        if constexpr (D % 16 == 0) {
            Xs[buf][xc + 0][xr] = px0.x; Xs[buf][xc + 1][xr] = px0.y;
            Xs[buf][xc + 2][xr] = px0.z; Xs[buf][xc + 3][xr] = px0.w;
            Xs[buf][xc + 4][xr] = px1.x; Xs[buf][xc + 5][xr] = px1.y;
            Xs[buf][xc + 6][xr] = px1.z; Xs[buf][xc + 7][xr] = px1.w;
            float4 v0, v1;
            if (isTop) {
                v0 = make_float4(wt0.x - wb0.x, wt0.y - wb0.y,
                                 wt0.z - wb0.z, wt0.w - wb0.w);
                v1 = make_float4(wt1.x - wb1.x, wt1.y - wb1.y,
                                 wt1.z - wb1.z, wt1.w - wb1.w);
            } else {
                v0 = wb0; v1 = wb1;
            }
            *(float4*)&Ws[buf][wk][mb]     = v0;
            *(float4*)&Ws[buf][wk][mb + 4] = v1;
        } else {
            #pragma unroll
            for (int u = 0; u < NXG; ++u) {
                const int e = t + u * 256;
                if (e < BM * KT) {
                    const int r = e / KT, c = e % KT;
                    Xs[buf][c][r] = pxg[u];
                }
            }
            #pragma unroll
            for (int u = 0; u < NWG; ++u) {
                const int e = t + u * 256;
                if (e < KT * 128) {
                    const int k = e >> 7, n = e & 127;
                    Ws[buf][k][wmap(n)] = pwg[u];
                }
            }
        }

        __syncthreads();   // BEFORE the load issue: nothing outstanding here

        // ---- issue next step's loads (drained only at NEXT step's
        //      ds_write, i.e. after this step's FMA block) ----
        if (s + 1 < NSTEP) {
            const int k0n = (s + 1) * KT;
            if constexpr (D % 16 == 0) {
                const float* xp = x + (size_t)(m0 + xr) * D + k0n + xc;
                px0 = *(const float4*)(xp);
                px1 = *(const float4*)(xp + 4);
                const float* pT = W + (size_t)(k0n + wk) * C + wcol;
                const float* pB = W + (size_t)(D + k0n + wk) * C + wcol;
                wt0 = *(const float4*)(pT); wt1 = *(const float4*)(pT + 4);
                wb0 = *(const float4*)(pB); wb1 = *(const float4*)(pB + 4);
            } else {
                #pragma unroll
                for (int u = 0; u < NXG; ++u) {
                    const int e = t + u * 256;
                    if (e < BM * KT) {
                        const int r = e / KT, c = e % KT;
                        pxg[u] = x[(size_t)(m0 + r) * D + k0n + c];
                    }
                }
                #pragma unroll
                for (int u = 0; u < NWG; ++u) {
                    const int e = t + u * 256;
                    if (e < KT * 128) {
                        const int k = e >> 7, n = e & 127;
                        const int g2 = n0 + n;
                        pwg[u] = (g2 < C)
                            ? W[(size_t)(k0n + k) * C + g2] - W[(size_t)(D + k0n + k) * C + g2]
                            : W[(size_t)(D + k0n + k) * C + (g2 - C)];
                    }
                }
            }
        }

        const int mc = wmap(tx * 8);
        #pragma unroll
        for (int kk = 0; kk < KT; ++kk) {
            float xm[8], wn[8];
            *(float4*)&xm[0] = *(const float4*)&Xs[buf][kk][ty * 8];
            *(float4*)&xm[4] = *(const float4*)&Xs[buf][kk][ty * 8 + 4];
            *(float4*)&wn[0] = *(const float4*)&Ws[buf][kk][mc];
            *(float4*)&wn[4] = *(const float4*)&Ws[buf][kk][mc + 4];
            #pragma unroll
            for (int m = 0; m < 8; ++m)
                #pragma unroll
                for (int n = 0; n < 8; ++n)
                    acc[m][n] = fmaf(xm[m], wn[n], acc[m][n]);
        }
        // no trailing barrier: next step writes the OTHER buffer.
    }

    if (isTop) {
        float fac[8];
        #pragma unroll
        for (int e = 0; e < 8; ++e) fac[e] = g[gn + e] * BN_SCALE_F;
        #pragma unroll
        for (int m = 0; m < 8; ++m) {
            float o[8];
            #pragma unroll
            for (int e = 0; e < 8; ++e) o[e] = fac[e] * acc[m][e];
            float* dst = A + (size_t)(m0 + ty * 8 + m) * C + gn;
            *(float4*)(dst)     = make_float4(o[0], o[1], o[2], o[3]);
            *(float4*)(dst + 4) = make_float4(o[4], o[5], o[6], o[7]);
        }
    } else {
        const int cb = gn - C;
        float fac[8], bb[8], bee[8];
        #pragma unroll
        for (int e = 0; e < 8; ++e) {
            fac[e] = g[cb + e] * BN_SCALE_F;
            bb[e]  = bias[cb + e];
            bee[e] = be[cb + e];
        }
        #pragma unroll
        for (int m = 0; m < 8; ++m) {
            float o[8];
            #pragma unroll
            for (int e = 0; e < 8; ++e)
                o[e] = fmaf(fac[e], acc[m][e] + bb[e], bee[e]);
            float* dst = Bv + (size_t)(m0 + ty * 8 + m) * C + cb;
            *(float4*)(dst)     = make_float4(o[0], o[1], o[2], o[3]);
            *(float4*)(dst + 4) = make_float4(o[4], o[5], o[6], o[7]);
        }
    }
}

// ---------------------------------------------------------------------------
// Combine v2 (float4): out[i][c] = relu(A[i][c] + max_k Bv[nbr[k]][c]).
// Per-channel fmax chain still ascending kk -> bit-identical.
// ---------------------------------------------------------------------------
template<int C>
__global__ __launch_bounds__(256) void combine_kernel(
        const float* A, const float* __restrict__ Bv,
        const int* __restrict__ idx, float* out) {
    constexpr int CQ = C / 4;          // float4 lanes per point
    constexpr int G  = 256 / CQ;       // points per block
    const int tid = threadIdx.x;
    const int bi0 = blockIdx.x * G;
    __shared__ int nbr[G * KNN];
    if (tid < G * KNN) {
        const int p = tid >> 4, kk = tid & 15;
        nbr[p * KNN + kk] = idx[(size_t)(bi0 + p) * KNN + kk];
    }
    __syncthreads();
    const int p = tid / CQ;
    const int q = tid % CQ;
    const int gi = bi0 + p;
    const int b0 = gi & ~255;          // batch base point index
    const float4* Bv4 = (const float4*)Bv;
    float4 mx = make_float4(-INFINITY, -INFINITY, -INFINITY, -INFINITY);
    #pragma unroll
    for (int kk = 0; kk < KNN; ++kk) {
        const int r = b0 + nbr[p * KNN + kk];
        const float4 v = Bv4[(size_t)r * CQ + q];
        mx.x = fmaxf(mx.x, v.x); mx.y = fmaxf(mx.y, v.y);
        mx.z = fmaxf(mx.z, v.z); mx.w = fmaxf(mx.w, v.w);
    }
    const float4 a = ((const float4*)A)[(size_t)gi * CQ + q];
    float4 o;
    o.x = fmaxf(a.x + mx.x, 0.f);
    o.y = fmaxf(a.y + mx.y, 0.f);
    o.z = fmaxf(a.z + mx.z, 0.f);
    o.w = fmaxf(a.w + mx.w, 0.f);
    ((float4*)out)[(size_t)gi * CQ + q] = o;
}

// ---------------------------------------------------------------------------
// Head v2: 1024 threads — 4-way partial max-pool per channel, LDS reduce,
// then the 2 tiny FCs. fmaxf associative on finite data -> bit-identical.
// ---------------------------------------------------------------------------
__global__ __launch_bounds__(1024) void head_kernel(
        const float* __restrict__ h3, const float* __restrict__ Wf1,
        const float* __restrict__ bf1, const float* __restrict__ gf,
        const float* __restrict__ bef, const float* __restrict__ Wf2,
        const float* __restrict__ bf2, float* __restrict__ out) {
    const int b   = blockIdx.x;
    const int tid = threadIdx.x;
    __shared__ float pp[4][256];
    __shared__ float p[256];
    __shared__ float f[128];
    const float* hb = h3 + (size_t)b * NPTS * 256;
    const int c  = tid & 255;
    const int q4 = tid >> 8;           // quarter 0..3
    float mx = -INFINITY;
    for (int n = q4 * 64; n < q4 * 64 + 64; ++n)
        mx = fmaxf(mx, hb[(size_t)n * 256 + c]);
    pp[q4][c] = mx;
    __syncthreads();
    if (tid < 256)
        p[tid] = fmaxf(fmaxf(pp[0][tid], pp[1][tid]),
                       fmaxf(pp[2][tid], pp[3][tid]));
    __syncthreads();
    if (tid < 128) {
        float acc = bf1[tid];
        for (int d = 0; d < 256; ++d)
            acc = fmaf(p[d], Wf1[(size_t)d * 128 + tid], acc);
        float v = gf[tid] * (acc * BN_SCALE_F) + bef[tid];
        f[tid] = fmaxf(v, 0.f);
    }
    __syncthreads();
    if (tid < 12) {
        float acc = bf2[tid];
        for (int d = 0; d < 128; ++d)
            acc = fmaf(f[d], Wf2[(size_t)d * 12 + tid], acc);
        out[(size_t)b * 12 + tid] = acc;
    }
}

extern "C" void kernel_launch(void* const* d_in, const int* in_sizes, int n_in,
                              void* d_out, int out_size, void* d_ws, size_t ws_size,
                              hipStream_t stream) {
    const float* x   = (const float*)d_in[0];
    const float* W1  = (const float*)d_in[1];
    const float* b1  = (const float*)d_in[2];
    const float* g1  = (const float*)d_in[3];
    const float* be1 = (const float*)d_in[4];
    const float* W2  = (const float*)d_in[5];
    const float* b2  = (const float*)d_in[6];
    const float* g2  = (const float*)d_in[7];
    const float* be2 = (const float*)d_in[8];
    const float* W3  = (const float*)d_in[9];
    const float* b3  = (const float*)d_in[10];
    const float* g3  = (const float*)d_in[11];
    const float* be3 = (const float*)d_in[12];
    const float* Wf1 = (const float*)d_in[13];
    const float* bf1 = (const float*)d_in[14];
    const float* gf  = (const float*)d_in[15];
    const float* bef = (const float*)d_in[16];
    const float* Wf2 = (const float*)d_in[17];
    const float* bf2 = (const float*)d_in[18];
    float* out = (float*)d_out;

    char* ws = (char*)d_ws;
    const size_t idx_bytes = (size_t)NBATCH * NPTS * KNN * sizeof(int);   // 2 MB
    const size_t reg_bytes = (size_t)NBATCH * NPTS * 256 * sizeof(float); // 32 MB
    int*   idx = (int*)ws;
    float* R1  = (float*)(ws + idx_bytes);
    float* R2  = (float*)(ws + idx_bytes + reg_bytes);
    float* R3  = (float*)(ws + idx_bytes + 2 * reg_bytes);

    const int BN = NBATCH * NPTS;        // 32768 points
    const int KNN_GRID = NBATCH * 2;     // 256 blocks (128 i-rows, 1024 thr)
    const int MB = BN / 128;             // 256 m-blocks for the MLP GEMM

    // ---- Layer 1: x (D=6) -> h1 (C=64) in R1 ----
    knn_fused_kernel<6><<<KNN_GRID, 1024, 0, stream>>>(x, idx);
    mlp_gemm_kernel<6, 64><<<dim3(MB, 1), 256, 0, stream>>>(
        x, W1, b1, g1, be1, R1, R2);
    combine_kernel<64><<<BN / 16, 256, 0, stream>>>(R1, R2, idx, R1);   // h1 = R1

    // ---- Layer 2: h1 (D=64) -> h2 (C=128) in R2 ----
    knn_fused_kernel<64><<<KNN_GRID, 1024, 0, stream>>>(R1, idx);
    mlp_gemm_kernel<64, 128><<<dim3(MB, 2), 256, 0, stream>>>(
        R1, W2, b2, g2, be2, R2, R3);
    combine_kernel<128><<<BN / 8, 256, 0, stream>>>(R2, R3, idx, R2);   // h2 = R2

    // ---- Layer 3: h2 (D=128) -> h3 (C=256) in R3 ----
    knn_fused_kernel<128><<<KNN_GRID, 1024, 0, stream>>>(R2, idx);
    mlp_gemm_kernel<128, 256><<<dim3(MB, 4), 256, 0, stream>>>(
        R2, W3, b3, g3, be3, R3, R1);
    combine_kernel<256><<<BN / 4, 256, 0, stream>>>(R3, R1, idx, R3);   // h3 = R3

    // ---- Head ----
    head_kernel<<<NBATCH, 1024, 0, stream>>>(R3, Wf1, bf1, gf, bef, Wf2, bf2, out);
}

// Round 18
// 397.505 us; speedup vs baseline: 1.2241x; 1.2241x over previous
//
#include <hip/hip_runtime.h>
#include <cstdint>
#include <cstddef>

#define KNN 16
#define NPTS 256
#define NBATCH 128

static constexpr float BN_SCALE_F = 0.9999950000374997f; // 1/sqrt(1+1e-5)

__device__ inline unsigned int f32_ord(float f) {
    unsigned int u = __float_as_uint(f);
    return (u & 0x80000000u) ? ~u : (u | 0x80000000u);
}

// Ws column gap map: 16-blocks shifted by 4 banks.
__device__ __forceinline__ int wmap(int n) { return n + 4 * (n >> 4); }

// ---------------------------------------------------------------------------
// FUSED kNN v9s (EXACT round-16 version — best measured, 400.8 us total).
// Round-17's 1024-thread v11 hit the VGPR wall (launch_bounds(1024) caps at
// 64 VGPR -> acc spilled, WRITE_SIZE 7->191 MB, dur 66->112 us) and is
// reverted per the pre-committed tripwire. 512-thread block (8 waves =
// 2 waves/SIMD) is the measured optimum of this design space.
// ---------------------------------------------------------------------------
template<int D>
__global__ __launch_bounds__(512) void knn_fused_kernel(
        const float* __restrict__ x, int* __restrict__ idx) {
    constexpr int KS = (D >= 16) ? 16 : D;
    constexpr int NSTEP = D / KS;                    // 8 / 4 / 1
    constexpr int NLA = (128 * KS + 511) / 512;      // generic A loads
    constexpr int NLB = (256 * KS + 511) / 512;      // generic B loads
    const int t  = threadIdx.x;
    const int tx = t & 31, ty = t >> 5;
    const int sr = t >> 2, sch = t & 3;
    const int b  = blockIdx.x >> 1;
    const int i0 = (blockIdx.x & 1) * 128;
    const int base = b * NPTS;

    __shared__ float As[2][KS][132];         // 128-row A k-slab, dbuf
    __shared__ float Bs[2][KS][260];         // 256-row B k-slab, dbuf
    __shared__ float d2L[128][132];          // per-phase d2 + merge values
    __shared__ unsigned char Mi[128][68];    // merge indices (j < 256)
    __shared__ float sqS[256];               // in-kernel sq (was global)

    // ---- prefetch registers; issue loads for slab s=0 ----
    float4 pa, pb[2];
    float  pas[NLA], pbs[NLB];
    if constexpr (D % 16 == 0) {
        {
            const int r = t >> 2, cq = (t & 3) * 4;
            pa = *(const float4*)(x + (size_t)(base + i0 + r) * D + cq);
        }
        #pragma unroll
        for (int u = 0; u < 2; ++u) {
            const int e = t + u * 512, r = e >> 2, cq = (e & 3) * 4;
            pb[u] = *(const float4*)(x + (size_t)(base + r) * D + cq);
        }
    } else {
        #pragma unroll
        for (int u = 0; u < NLA; ++u) {
            const int e = t + u * 512;
            if (e < 128 * KS) {
                const int r = e / KS, c = e % KS;
                pas[u] = x[(size_t)(base + i0 + r) * D + c];
            }
        }
        #pragma unroll
        for (int u = 0; u < NLB; ++u) {
            const int e = t + u * 512;
            if (e < 256 * KS) {
                const int r = e / KS, c = e % KS;
                pbs[u] = x[(size_t)(base + r) * D + c];
            }
        }
    }

    // ---- compute sq for all 256 batch points (same fmaf chain as the old
    //      sq_kernel: d ascending per point -> identical bits) ----
    if (t < 256) {
        const float* r = x + (size_t)(base + t) * D;
        float ssum = 0.f;
        #pragma unroll
        for (int d = 0; d < D; ++d) ssum = fmaf(r[d], r[d], ssum);
        sqS[t] = ssum;
    }
    __syncthreads();

    // ---- hoist sqi (phase-invariant) ----
    float sqi[8];
    #pragma unroll
    for (int m = 0; m < 8; ++m) sqi[m] = sqS[i0 + ty * 8 + m];

    float acc[8][8] = {};

    for (int s = 0; s < NSTEP; ++s) {
        const int buf = s & 1;
        // ---- write prefetched A/B slabs into buf ----
        if constexpr (D % 16 == 0) {
            {
                const int r = t >> 2, cq = (t & 3) * 4;
                As[buf][cq + 0][r] = pa.x; As[buf][cq + 1][r] = pa.y;
                As[buf][cq + 2][r] = pa.z; As[buf][cq + 3][r] = pa.w;
            }
            #pragma unroll
            for (int u = 0; u < 2; ++u) {
                const int e = t + u * 512, r = e >> 2, cq = (e & 3) * 4;
                Bs[buf][cq + 0][r] = pb[u].x; Bs[buf][cq + 1][r] = pb[u].y;
                Bs[buf][cq + 2][r] = pb[u].z; Bs[buf][cq + 3][r] = pb[u].w;
            }
        } else {
            #pragma unroll
            for (int u = 0; u < NLA; ++u) {
                const int e = t + u * 512;
                if (e < 128 * KS) {
                    const int r = e / KS, c = e % KS;
                    As[buf][c][r] = pas[u];
                }
            }
            #pragma unroll
            for (int u = 0; u < NLB; ++u) {
                const int e = t + u * 512;
                if (e < 256 * KS) {
                    const int r = e / KS, c = e % KS;
                    Bs[buf][c][r] = pbs[u];
                }
            }
        }

        // ---- issue next slab's loads (hide under FMA block below) ----
        if (s + 1 < NSTEP) {
            const int k0n = (s + 1) * KS;
            if constexpr (D % 16 == 0) {
                {
                    const int r = t >> 2, cq = (t & 3) * 4;
                    pa = *(const float4*)(x + (size_t)(base + i0 + r) * D + k0n + cq);
                }
                #pragma unroll
                for (int u = 0; u < 2; ++u) {
                    const int e = t + u * 512, r = e >> 2, cq = (e & 3) * 4;
                    pb[u] = *(const float4*)(x + (size_t)(base + r) * D + k0n + cq);
                }
            } else {
                #pragma unroll
                for (int u = 0; u < NLA; ++u) {
                    const int e = t + u * 512;
                    if (e < 128 * KS) {
                        const int r = e / KS, c = e % KS;
                        pas[u] = x[(size_t)(base + i0 + r) * D + k0n + c];
                    }
                }
                #pragma unroll
                for (int u = 0; u < NLB; ++u) {
                    const int e = t + u * 512;
                    if (e < 256 * KS) {
                        const int r = e / KS, c = e % KS;
                        pbs[u] = x[(size_t)(base + r) * D + k0n + c];
                    }
                }
            }
        }

        __syncthreads();   // the ONLY barrier in the slab step

        // ---- gram FMAs (k ascending); B-frag scalar lane==bank reads ----
        #pragma unroll
        for (int kk = 0; kk < KS; ++kk) {
            float am[8], bm[8];
            *(float4*)&am[0] = *(const float4*)&As[buf][kk][ty * 8];      // bcast
            *(float4*)&am[4] = *(const float4*)&As[buf][kk][ty * 8 + 4];  // bcast
            #pragma unroll
            for (int n = 0; n < 8; ++n)
                bm[n] = Bs[buf][kk][n * 32 + tx];  // bank = tx: conflict-free
            #pragma unroll
            for (int m = 0; m < 8; ++m)
                #pragma unroll
                for (int n = 0; n < 8; ++n)
                    acc[m][n] = fmaf(am[m], bm[n], acc[m][n]);
        }
        // no trailing barrier: next slab writes the OTHER buffer.
    }

    unsigned int Lv[16], Li[16];
    #pragma unroll
    for (int q = 0; q < 16; ++q) { Lv[q] = 0xFFFFFFFFu; Li[q] = 0u; }

    // ==== two 128-col phases: epilogue write + insertion scan ====
    #pragma unroll
    for (int ph = 0; ph < 2; ++ph) {
        float sqj[4];
        #pragma unroll
        for (int n2 = 0; n2 < 4; ++n2)
            sqj[n2] = sqS[ph * 128 + n2 * 32 + tx];
        #pragma unroll
        for (int m = 0; m < 8; ++m) {
            const int gi = i0 + ty * 8 + m;
            #pragma unroll
            for (int n2 = 0; n2 < 4; ++n2) {
                float v = (sqi[m] + sqj[n2]) - 2.f * acc[m][ph * 4 + n2];
                if (gi == ph * 128 + n2 * 32 + tx) v = INFINITY;
                d2L[ty * 8 + m][n2 * 32 + tx] = v;
            }
        }
        __syncthreads();

        // ---- insertion: thread (sr, sch) scans j = ph*128 + sch + 4i ----
        #pragma unroll 4
        for (int i = 0; i < 32; ++i) {
            const unsigned int v = f32_ord(d2L[sr][sch + 4 * i]);
            const unsigned int j = (unsigned int)(ph * 128 + sch + 4 * i);
            #pragma unroll
            for (int q = 15; q >= 1; --q) {
                const bool a = v < Lv[q];
                const bool c = v < Lv[q - 1];
                Lv[q] = a ? (c ? Lv[q - 1] : v) : Lv[q];
                Li[q] = a ? (c ? Li[q - 1] : j) : Li[q];
            }
            const bool a0 = v < Lv[0];
            Lv[0] = a0 ? v : Lv[0];
            Li[0] = a0 ? j : Li[0];
        }
        __syncthreads();   // insertion done before d2L is overwritten
    }

    // ---- merge staging: channel lists into d2L/Mi ----
    #pragma unroll
    for (int q = 0; q < 16; ++q) {
        d2L[sr][sch * 16 + q] = __uint_as_float(Lv[q]);
        Mi[sr][sch * 16 + q]  = (unsigned char)Li[q];
    }
    __syncthreads();

    if (t < 128) {
        const int row = t;
        int h[4];
        unsigned int cv[4], ci[4];
        #pragma unroll
        for (int c = 0; c < 4; ++c) {
            h[c]  = 0;
            cv[c] = __float_as_uint(d2L[row][c * 16]);
            ci[c] = Mi[row][c * 16];
        }
        int outj[16];
        #pragma unroll
        for (int rd = 0; rd < 16; ++rd) {
            unsigned int bv = cv[0], bi = ci[0];
            int bc = 0;
            #pragma unroll
            for (int c = 1; c < 4; ++c) {
                const bool tk = (cv[c] < bv) | ((cv[c] == bv) & (ci[c] < bi));
                bv = tk ? cv[c] : bv;
                bi = tk ? ci[c] : bi;
                bc = tk ? c     : bc;
            }
            outj[rd] = (int)bi;
            #pragma unroll
            for (int c = 0; c < 4; ++c) {
                if (c == bc) {
                    const int hn = h[c] + 1;
                    h[c] = hn;
                    if (hn < 16) {
                        cv[c] = __float_as_uint(d2L[row][c * 16 + hn]);
                        ci[c] = Mi[row][c * 16 + hn];
                    } else {
                        cv[c] = 0xFFFFFFFFu;
                    }
                }
            }
        }
        int4* op = (int4*)(idx + (size_t)(base + i0 + row) * KNN);
        op[0] = make_int4(outj[0],  outj[1],  outj[2],  outj[3]);
        op[1] = make_int4(outj[4],  outj[5],  outj[6],  outj[7]);
        op[2] = make_int4(outj[8],  outj[9],  outj[10], outj[11]);
        op[3] = make_int4(outj[12], outj[13], outj[14], outj[15]);
    }
}

// ---------------------------------------------------------------------------
// Factorized edge-MLP GEMM v2c (round-14/15/16 version — best measured mlp):
// 256 thr, BM=128, double-buffered, barrier BEFORE the load issue.
// Bit-identical output.
// ---------------------------------------------------------------------------
template<int D, int C>
__global__ __launch_bounds__(256) void mlp_gemm_kernel(
        const float* __restrict__ x, const float* __restrict__ W,
        const float* __restrict__ bias, const float* __restrict__ g,
        const float* __restrict__ be,
        float* __restrict__ A, float* __restrict__ Bv) {
    constexpr int BM = 128;
    constexpr int KT = (D >= 16) ? 16 : D;
    constexpr int NSTEP = D / KT;                    // 8 / 4 / 1
    constexpr int NXG = (BM * KT + 255) / 256;       // generic X loads
    constexpr int NWG = (KT * 128 + 255) / 256;      // generic W loads
    const int t  = threadIdx.x;
    const int tx = t & 15;   // col group (8 cols)
    const int ty = t >> 4;   // row group (8 rows)
    const int m0 = blockIdx.x * BM;
    const int n0 = blockIdx.y * 128;

    __shared__ float Xs[2][KT][132];
    __shared__ float Ws[2][KT][164];   // stride 164 == 4 mod 32

    float acc[8][8] = {};

    // staging roles (fast path)
    const int xr = t >> 1, xc = (t & 1) * 8;   // X: row 0..127, col 0 or 8
    const int wk = t >> 4, nq = (t & 15) * 8;  // W: k-row 0..15, col-8-block
    const int gn = n0 + nq;
    const bool isTop = (gn < C);
    const int wcol = isTop ? gn : (gn - C);
    const int mb = wmap(nq);

    // prefetch registers
    float4 px0, px1;             // X slab: 8 floats
    float4 wt0, wt1, wb0, wb1;   // W slab: top + bottom, raw
    float  pxg[NXG], pwg[NWG];   // generic path

    // ---- issue loads for step s=0 ----
    if constexpr (D % 16 == 0) {
        const float* xp = x + (size_t)(m0 + xr) * D + xc;
        px0 = *(const float4*)(xp);
        px1 = *(const float4*)(xp + 4);
        const float* pT = W + (size_t)wk * C + wcol;        // top rows (unused if !isTop)
        const float* pB = W + (size_t)(D + wk) * C + wcol;  // bottom rows
        wt0 = *(const float4*)(pT); wt1 = *(const float4*)(pT + 4);
        wb0 = *(const float4*)(pB); wb1 = *(const float4*)(pB + 4);
    } else {
        #pragma unroll
        for (int u = 0; u < NXG; ++u) {
            const int e = t + u * 256;
            if (e < BM * KT) {
                const int r = e / KT, c = e % KT;
                pxg[u] = x[(size_t)(m0 + r) * D + c];
            }
        }
        #pragma unroll
        for (int u = 0; u < NWG; ++u) {
            const int e = t + u * 256;
            if (e < KT * 128) {
                const int k = e >> 7, n = e & 127;
                const int g2 = n0 + n;
                pwg[u] = (g2 < C)
                    ? W[(size_t)k * C + g2] - W[(size_t)(D + k) * C + g2]
                    : W[(size_t)(D + k) * C + (g2 - C)];
            }
        }
    }

    for (int s = 0; s < NSTEP; ++s) {
        const int buf = s & 1;
        // ---- write staged slabs (loaded last step) into buf ----
        if constexpr (D % 16 == 0) {
            Xs[buf][xc + 0][xr] = px0.x; Xs[buf][xc + 1][xr] = px0.y;
            Xs[buf][xc + 2][xr] = px0.z; Xs[buf][xc + 3][xr] = px0.w;
            Xs[buf][xc + 4][xr] = px1.x; Xs[buf][xc + 5][xr] = px1.y;
            Xs[buf][xc + 6][xr] = px1.z; Xs[buf][xc + 7][xr] = px1.w;
            float4 v0, v1;
            if (isTop) {
                v0 = make_float4(wt0.x - wb0.x, wt0.y - wb0.y,
                                 wt0.z - wb0.z, wt0.w - wb0.w);
                v1 = make_float4(wt1.x - wb1.x, wt1.y - wb1.y,
                                 wt1.z - wb1.z, wt1.w - wb1.w);
            } else {
                v0 = wb0; v1 = wb1;
            }
            *(float4*)&Ws[buf][wk][mb]     = v0;
            *(float4*)&Ws[buf][wk][mb + 4] = v1;
        } else {
            #pragma unroll
            for (int u = 0; u < NXG; ++u) {
                const int e = t + u * 256;
                if (e < BM * KT) {
                    const int r = e / KT, c = e % KT;
                    Xs[buf][c][r] = pxg[u];
                }
            }
            #pragma unroll
            for (int u = 0; u < NWG; ++u) {
                const int e = t + u * 256;
                if (e < KT * 128) {
                    const int k = e >> 7, n = e & 127;
                    Ws[buf][k][wmap(n)] = pwg[u];
                }
            }
        }

        __syncthreads();   // BEFORE the load issue: nothing outstanding here

        // ---- issue next step's loads (drained only at NEXT step's
        //      ds_write, i.e. after this step's FMA block) ----
        if (s + 1 < NSTEP) {
            const int k0n = (s + 1) * KT;
            if constexpr (D % 16 == 0) {
                const float* xp = x + (size_t)(m0 + xr) * D + k0n + xc;
                px0 = *(const float4*)(xp);
                px1 = *(const float4*)(xp + 4);
                const float* pT = W + (size_t)(k0n + wk) * C + wcol;
                const float* pB = W + (size_t)(D + k0n + wk) * C + wcol;
                wt0 = *(const float4*)(pT); wt1 = *(const float4*)(pT + 4);
                wb0 = *(const float4*)(pB); wb1 = *(const float4*)(pB + 4);
            } else {
                #pragma unroll
                for (int u = 0; u < NXG; ++u) {
                    const int e = t + u * 256;
                    if (e < BM * KT) {
                        const int r = e / KT, c = e % KT;
                        pxg[u] = x[(size_t)(m0 + r) * D + k0n + c];
                    }
                }
                #pragma unroll
                for (int u = 0; u < NWG; ++u) {
                    const int e = t + u * 256;
                    if (e < KT * 128) {
                        const int k = e >> 7, n = e & 127;
                        const int g2 = n0 + n;
                        pwg[u] = (g2 < C)
                            ? W[(size_t)(k0n + k) * C + g2] - W[(size_t)(D + k0n + k) * C + g2]
                            : W[(size_t)(D + k0n + k) * C + (g2 - C)];
                    }
                }
            }
        }

        const int mc = wmap(tx * 8);
        #pragma unroll
        for (int kk = 0; kk < KT; ++kk) {
            float xm[8], wn[8];
            *(float4*)&xm[0] = *(const float4*)&Xs[buf][kk][ty * 8];
            *(float4*)&xm[4] = *(const float4*)&Xs[buf][kk][ty * 8 + 4];
            *(float4*)&wn[0] = *(const float4*)&Ws[buf][kk][mc];
            *(float4*)&wn[4] = *(const float4*)&Ws[buf][kk][mc + 4];
            #pragma unroll
            for (int m = 0; m < 8; ++m)
                #pragma unroll
                for (int n = 0; n < 8; ++n)
                    acc[m][n] = fmaf(xm[m], wn[n], acc[m][n]);
        }
        // no trailing barrier: next step writes the OTHER buffer.
    }

    if (isTop) {
        float fac[8];
        #pragma unroll
        for (int e = 0; e < 8; ++e) fac[e] = g[gn + e] * BN_SCALE_F;
        #pragma unroll
        for (int m = 0; m < 8; ++m) {
            float o[8];
            #pragma unroll
            for (int e = 0; e < 8; ++e) o[e] = fac[e] * acc[m][e];
            float* dst = A + (size_t)(m0 + ty * 8 + m) * C + gn;
            *(float4*)(dst)     = make_float4(o[0], o[1], o[2], o[3]);
            *(float4*)(dst + 4) = make_float4(o[4], o[5], o[6], o[7]);
        }
    } else {
        const int cb = gn - C;
        float fac[8], bb[8], bee[8];
        #pragma unroll
        for (int e = 0; e < 8; ++e) {
            fac[e] = g[cb + e] * BN_SCALE_F;
            bb[e]  = bias[cb + e];
            bee[e] = be[cb + e];
        }
        #pragma unroll
        for (int m = 0; m < 8; ++m) {
            float o[8];
            #pragma unroll
            for (int e = 0; e < 8; ++e)
                o[e] = fmaf(fac[e], acc[m][e] + bb[e], bee[e]);
            float* dst = Bv + (size_t)(m0 + ty * 8 + m) * C + cb;
            *(float4*)(dst)     = make_float4(o[0], o[1], o[2], o[3]);
            *(float4*)(dst + 4) = make_float4(o[4], o[5], o[6], o[7]);
        }
    }
}

// ---------------------------------------------------------------------------
// Combine v2 (float4): out[i][c] = relu(A[i][c] + max_k Bv[nbr[k]][c]).
// Per-channel fmax chain still ascending kk -> bit-identical.
// ---------------------------------------------------------------------------
template<int C>
__global__ __launch_bounds__(256) void combine_kernel(
        const float* A, const float* __restrict__ Bv,
        const int* __restrict__ idx, float* out) {
    constexpr int CQ = C / 4;          // float4 lanes per point
    constexpr int G  = 256 / CQ;       // points per block
    const int tid = threadIdx.x;
    const int bi0 = blockIdx.x * G;
    __shared__ int nbr[G * KNN];
    if (tid < G * KNN) {
        const int p = tid >> 4, kk = tid & 15;
        nbr[p * KNN + kk] = idx[(size_t)(bi0 + p) * KNN + kk];
    }
    __syncthreads();
    const int p = tid / CQ;
    const int q = tid % CQ;
    const int gi = bi0 + p;
    const int b0 = gi & ~255;          // batch base point index
    const float4* Bv4 = (const float4*)Bv;
    float4 mx = make_float4(-INFINITY, -INFINITY, -INFINITY, -INFINITY);
    #pragma unroll
    for (int kk = 0; kk < KNN; ++kk) {
        const int r = b0 + nbr[p * KNN + kk];
        const float4 v = Bv4[(size_t)r * CQ + q];
        mx.x = fmaxf(mx.x, v.x); mx.y = fmaxf(mx.y, v.y);
        mx.z = fmaxf(mx.z, v.z); mx.w = fmaxf(mx.w, v.w);
    }
    const float4 a = ((const float4*)A)[(size_t)gi * CQ + q];
    float4 o;
    o.x = fmaxf(a.x + mx.x, 0.f);
    o.y = fmaxf(a.y + mx.y, 0.f);
    o.z = fmaxf(a.z + mx.z, 0.f);
    o.w = fmaxf(a.w + mx.w, 0.f);
    ((float4*)out)[(size_t)gi * CQ + q] = o;
}

// ---------------------------------------------------------------------------
// Head v2: 1024 threads — 4-way partial max-pool per channel, LDS reduce,
// then the 2 tiny FCs. fmaxf associative on finite data -> bit-identical.
// ---------------------------------------------------------------------------
__global__ __launch_bounds__(1024) void head_kernel(
        const float* __restrict__ h3, const float* __restrict__ Wf1,
        const float* __restrict__ bf1, const float* __restrict__ gf,
        const float* __restrict__ bef, const float* __restrict__ Wf2,
        const float* __restrict__ bf2, float* __restrict__ out) {
    const int b   = blockIdx.x;
    const int tid = threadIdx.x;
    __shared__ float pp[4][256];
    __shared__ float p[256];
    __shared__ float f[128];
    const float* hb = h3 + (size_t)b * NPTS * 256;
    const int c  = tid & 255;
    const int q4 = tid >> 8;           // quarter 0..3
    float mx = -INFINITY;
    for (int n = q4 * 64; n < q4 * 64 + 64; ++n)
        mx = fmaxf(mx, hb[(size_t)n * 256 + c]);
    pp[q4][c] = mx;
    __syncthreads();
    if (tid < 256)
        p[tid] = fmaxf(fmaxf(pp[0][tid], pp[1][tid]),
                       fmaxf(pp[2][tid], pp[3][tid]));
    __syncthreads();
    if (tid < 128) {
        float acc = bf1[tid];
        for (int d = 0; d < 256; ++d)
            acc = fmaf(p[d], Wf1[(size_t)d * 128 + tid], acc);
        float v = gf[tid] * (acc * BN_SCALE_F) + bef[tid];
        f[tid] = fmaxf(v, 0.f);
    }
    __syncthreads();
    if (tid < 12) {
        float acc = bf2[tid];
        for (int d = 0; d < 128; ++d)
            acc = fmaf(f[d], Wf2[(size_t)d * 12 + tid], acc);
        out[(size_t)b * 12 + tid] = acc;
    }
}

extern "C" void kernel_launch(void* const* d_in, const int* in_sizes, int n_in,
                              void* d_out, int out_size, void* d_ws, size_t ws_size,
                              hipStream_t stream) {
    const float* x   = (const float*)d_in[0];
    const float* W1  = (const float*)d_in[1];
    const float* b1  = (const float*)d_in[2];
    const float* g1  = (const float*)d_in[3];
    const float* be1 = (const float*)d_in[4];
    const float* W2  = (const float*)d_in[5];
    const float* b2  = (const float*)d_in[6];
    const float* g2  = (const float*)d_in[7];
    const float* be2 = (const float*)d_in[8];
    const float* W3  = (const float*)d_in[9];
    const float* b3  = (const float*)d_in[10];
    const float* g3  = (const float*)d_in[11];
    const float* be3 = (const float*)d_in[12];
    const float* Wf1 = (const float*)d_in[13];
    const float* bf1 = (const float*)d_in[14];
    const float* gf  = (const float*)d_in[15];
    const float* bef = (const float*)d_in[16];
    const float* Wf2 = (const float*)d_in[17];
    const float* bf2 = (const float*)d_in[18];
    float* out = (float*)d_out;

    char* ws = (char*)d_ws;
    const size_t idx_bytes = (size_t)NBATCH * NPTS * KNN * sizeof(int);   // 2 MB
    const size_t reg_bytes = (size_t)NBATCH * NPTS * 256 * sizeof(float); // 32 MB
    int*   idx = (int*)ws;
    float* R1  = (float*)(ws + idx_bytes);
    float* R2  = (float*)(ws + idx_bytes + reg_bytes);
    float* R3  = (float*)(ws + idx_bytes + 2 * reg_bytes);

    const int BN = NBATCH * NPTS;        // 32768 points
    const int KNN_GRID = NBATCH * 2;     // 256 blocks (128 i-rows, 512 thr)
    const int MB = BN / 128;             // 256 m-blocks for the MLP GEMM

    // ---- Layer 1: x (D=6) -> h1 (C=64) in R1 ----
    knn_fused_kernel<6><<<KNN_GRID, 512, 0, stream>>>(x, idx);
    mlp_gemm_kernel<6, 64><<<dim3(MB, 1), 256, 0, stream>>>(
        x, W1, b1, g1, be1, R1, R2);
    combine_kernel<64><<<BN / 16, 256, 0, stream>>>(R1, R2, idx, R1);   // h1 = R1

    // ---- Layer 2: h1 (D=64) -> h2 (C=128) in R2 ----
    knn_fused_kernel<64><<<KNN_GRID, 512, 0, stream>>>(R1, idx);
    mlp_gemm_kernel<64, 128><<<dim3(MB, 2), 256, 0, stream>>>(
        R1, W2, b2, g2, be2, R2, R3);
    combine_kernel<128><<<BN / 8, 256, 0, stream>>>(R2, R3, idx, R2);   // h2 = R2

    // ---- Layer 3: h2 (D=128) -> h3 (C=256) in R3 ----
    knn_fused_kernel<128><<<KNN_GRID, 512, 0, stream>>>(R2, idx);
    mlp_gemm_kernel<128, 256><<<dim3(MB, 4), 256, 0, stream>>>(
        R2, W3, b3, g3, be3, R3, R1);
    combine_kernel<256><<<BN / 4, 256, 0, stream>>>(R3, R1, idx, R3);   // h3 = R3

    // ---- Head ----
    head_kernel<<<NBATCH, 1024, 0, stream>>>(R3, Wf1, bf1, gf, bef, Wf2, bf2, out);
}